// Round 17
// baseline (158.560 us; speedup 1.0000x reference)
//
#include <hip/hip_runtime.h>

#define N_ 32
#define C_ 64
#define T_ 400
#define V_ 27
#define S_ 2
#define CI_ 16
#define CO_ 64
#define TCHUNK 8
#define NCHUNK 50
#define ATT_N 1458           // S_*V_*V_
#define P_ 10800             // T_*V_
#define PT_ 10816            // 169*64
#define QTILES 85            // ceil(P_/128)
#define HGUARD 32
#define HROWS 10944          // HGUARD + P_ + 112

typedef short bhalf8 __attribute__((ext_vector_type(8)));
typedef float fx4 __attribute__((ext_vector_type(4)));

static __device__ inline unsigned short f2bf(float f) {
  return __builtin_bit_cast(unsigned short, (__bf16)f);
}
static __device__ inline unsigned pk2bf(float lo, float hi) {
  return (unsigned)f2bf(lo) | ((unsigned)f2bf(hi) << 16);
}
static __device__ inline float bf2f(unsigned short h) {
  unsigned u = ((unsigned)h) << 16;
  return __builtin_bit_cast(float, u);
}

// ================= MFMA path =================

// kprep: bf16 weights (Wout|Wff|Wt|Wi), fused bn consts + b_in, zero h2T guards
__global__ __launch_bounds__(256) void kprep(
    const float* __restrict__ w_out, const float* __restrict__ w_ff,
    const float* __restrict__ w_t, const float* __restrict__ w_in,
    const float* __restrict__ b_out, const float* __restrict__ b_ff,
    const float* __restrict__ b_t, const float* __restrict__ b_in,
    const float* __restrict__ bn1_g, const float* __restrict__ bn1_b,
    const float* __restrict__ bn1_m, const float* __restrict__ bn1_v,
    const float* __restrict__ bn2_g, const float* __restrict__ bn2_b,
    const float* __restrict__ bn2_m, const float* __restrict__ bn2_v,
    const float* __restrict__ bn3_g, const float* __restrict__ bn3_b,
    const float* __restrict__ bn3_m, const float* __restrict__ bn3_v,
    unsigned short* __restrict__ Wb, float* __restrict__ cst,
    unsigned short* __restrict__ h2Tg)
{
  const int tid = threadIdx.x;
  const int bid = blockIdx.x;
  uint4 z; z.x = 0; z.y = 0; z.z = 0; z.w = 0;
  for (int i = bid * 256 + tid; i < N_ * 1152; i += 64 * 256) {
    int n = i / 1152, r = i - n * 1152;
    size_t off = (r < 256) ? (size_t)r * 8 : (size_t)10832 * 64 + (size_t)(r - 256) * 8;
    *reinterpret_cast<uint4*>(h2Tg + (size_t)n * HROWS * 64 + off) = z;
  }
  if (bid != 0) return;
  for (int i = tid; i < 8192; i += 256) Wb[i] = f2bf(w_out[i]);
  for (int i = tid; i < 4096; i += 256) Wb[8192 + i] = f2bf(w_ff[i]);
  for (int i = tid; i < 12288; i += 256) {
    int o = i / 192, r = i - o * 192, dt = r >> 6, ic = r & 63;
    Wb[12288 + i] = f2bf(w_t[(size_t)(o * 64 + ic) * 3 + dt]);
  }
  for (int i = tid; i < 4096; i += 256) Wb[24576 + i] = f2bf(w_in[i]);
  if (tid < 64) {
    int o = tid;
    float a1 = bn1_g[o] * rsqrtf(bn1_v[o] + 1e-5f);
    cst[o] = a1;
    cst[64 + o] = (b_out[o] - bn1_m[o]) * a1 + bn1_b[o];
    float a2 = bn2_g[o] * rsqrtf(bn2_v[o] + 1e-5f);
    cst[128 + o] = a2;
    cst[192 + o] = (b_ff[o] - bn2_m[o]) * a2 + bn2_b[o];
    float a3 = bn3_g[o] * rsqrtf(bn3_v[o] + 1e-5f);
    cst[256 + o] = a3;
    cst[320 + o] = (b_t[o] - bn3_m[o]) * a3 + bn3_b[o];
    cst[384 + o] = b_in[o];
  }
}

// kpe: precompute qkpe[m][p][ci16] = Wi . pe + b_in  (fp32, n-independent)
__global__ __launch_bounds__(256) void kpe(
    const float* __restrict__ pe,
    const unsigned short* __restrict__ Wb,
    const float* __restrict__ cst,
    float* __restrict__ qkpe)
{
  const int p0 = blockIdx.x * 128;
  const int tid = threadIdx.x;
  const int w = tid >> 6;
  const int l = tid & 63;
  const int cl = l & 15;
  const int lq = l >> 4;

  __shared__ unsigned short xlb[64][132];
  __shared__ float clds[64];
  if (tid < 64) clds[tid] = cst[384 + tid];

  const int c_s = tid >> 5;
  const int c4_s = tid & 31;
  const int pp_s = p0 + c4_s * 4;

  if (p0 + 128 <= P_) {
#pragma unroll
    for (int k = 0; k < 8; ++k) {
      int c = k * 8 + c_s;
      float4 a = *reinterpret_cast<const float4*>(pe + (size_t)c * P_ + pp_s);
      uint2 d;
      d.x = pk2bf(a.x, a.y);
      d.y = pk2bf(a.z, a.w);
      *reinterpret_cast<uint2*>(&xlb[c][c4_s * 4]) = d;
    }
  } else {
#pragma unroll
    for (int k = 0; k < 8; ++k) {
      int c = k * 8 + c_s;
      const float* pr = pe + (size_t)c * P_;
      float v0 = (pp_s + 0 < P_) ? pr[pp_s + 0] : 0.f;
      float v1 = (pp_s + 1 < P_) ? pr[pp_s + 1] : 0.f;
      float v2 = (pp_s + 2 < P_) ? pr[pp_s + 2] : 0.f;
      float v3 = (pp_s + 3 < P_) ? pr[pp_s + 3] : 0.f;
      uint2 d;
      d.x = pk2bf(v0, v1);
      d.y = pk2bf(v2, v3);
      *reinterpret_cast<uint2*>(&xlb[c][c4_s * 4]) = d;
    }
  }
  __syncthreads();

  const unsigned short* Wi = Wb + 24576;
#pragma unroll
  for (int h = 0; h < 2; ++h) {
    const int rl = h * 64 + w * 16 + cl;
    const int p = p0 + rl;
    bhalf8 bfr[2];
#pragma unroll
    for (int ks = 0; ks < 2; ++ks) {
      unsigned* bu = reinterpret_cast<unsigned*>(&bfr[ks]);
#pragma unroll
      for (int j = 0; j < 4; ++j) {
        int c = ks * 32 + lq * 8 + 2 * j;
        bu[j] = (unsigned)xlb[c][rl] | ((unsigned)xlb[c + 1][rl] << 16);
      }
    }
    fx4 acc[4];
#pragma unroll
    for (int m = 0; m < 4; ++m) { acc[m][0]=0.f; acc[m][1]=0.f; acc[m][2]=0.f; acc[m][3]=0.f; }
#pragma unroll
    for (int m = 0; m < 4; ++m) {
#pragma unroll
      for (int ks = 0; ks < 2; ++ks) {
        bhalf8 a = *reinterpret_cast<const bhalf8*>(Wi + (m * 16 + cl) * 64 + ks * 32 + lq * 8);
        acc[m] = __builtin_amdgcn_mfma_f32_16x16x32_bf16(a, bfr[ks], acc[m], 0, 0, 0);
      }
    }
    if (p < P_) {
#pragma unroll
      for (int m = 0; m < 4; ++m) {
        float4 d;
        d.x = acc[m][0] + clds[m * 16 + lq * 4 + 0];
        d.y = acc[m][1] + clds[m * 16 + lq * 4 + 1];
        d.z = acc[m][2] + clds[m * 16 + lq * 4 + 2];
        d.w = acc[m][3] + clds[m * 16 + lq * 4 + 3];
        *reinterpret_cast<float4*>(qkpe + ((size_t)m * PT_ + p) * 16 + lq * 4) = d;
      }
    }
  }
}

// k1a2: DMA-staged fp32 x tile (global_load_lds) + qk = Wi.x + qkpe -> qk2
__global__ __launch_bounds__(256) void k1a2(
    const float* __restrict__ x,
    const unsigned short* __restrict__ Wb,
    const float* __restrict__ qkpe,
    unsigned short* __restrict__ qk2)
{
  const int n = blockIdx.x;
  const int p0 = blockIdx.y * 128;
  const int tid = threadIdx.x;
  const int w = tid >> 6;
  const int l = tid & 63;
  const int cl = l & 15;
  const int lq = l >> 4;

  __shared__ __align__(16) float xf[64][128];   // fp32 tile, LINEAR (DMA dest)

  if (p0 + 128 <= P_) {
    // fire-and-forget DMA: 8 calls/wave, each moves 2 rows (64 lanes x 16B = 1KB)
#pragma unroll
    for (int k = 0; k < 8; ++k) {
      const int rb = (k * 4 + w) * 2;
      const int c = rb + (l >> 5);
      const float* gsrc = x + ((size_t)(n * C_ + c)) * P_ + p0 + (l & 31) * 4;
      __builtin_amdgcn_global_load_lds(
          (const __attribute__((address_space(1))) void*)gsrc,
          (__attribute__((address_space(3))) void*)(&xf[rb][0]),
          16, 0, 0);
    }
  } else {
    const int c_s = tid >> 5;
    const int c4_s = tid & 31;
    const int pp_s = p0 + c4_s * 4;
#pragma unroll
    for (int k = 0; k < 8; ++k) {
      int c = k * 8 + c_s;
      const float* xr = x + (size_t)(n * C_ + c) * P_;
      xf[c][c4_s * 4 + 0] = (pp_s + 0 < P_) ? xr[pp_s + 0] : 0.f;
      xf[c][c4_s * 4 + 1] = (pp_s + 1 < P_) ? xr[pp_s + 1] : 0.f;
      xf[c][c4_s * 4 + 2] = (pp_s + 2 < P_) ? xr[pp_s + 2] : 0.f;
      xf[c][c4_s * 4 + 3] = (pp_s + 3 < P_) ? xr[pp_s + 3] : 0.f;
    }
  }
  __syncthreads();   // drains vmcnt (DMA) before any reads

  const unsigned short* Wi = Wb + 24576;
#pragma unroll
  for (int h = 0; h < 2; ++h) {
    const int rl = h * 64 + w * 16 + cl;
    const int p = p0 + rl;
    const int pc = (p < P_) ? p : (P_ - 1);
    float4 pkv[4];
#pragma unroll
    for (int m = 0; m < 4; ++m)
      pkv[m] = *reinterpret_cast<const float4*>(qkpe + ((size_t)m * PT_ + pc) * 16 + lq * 4);
    bhalf8 bfr[2];
#pragma unroll
    for (int ks = 0; ks < 2; ++ks) {
      unsigned* bu = reinterpret_cast<unsigned*>(&bfr[ks]);
#pragma unroll
      for (int j = 0; j < 4; ++j) {
        int c = ks * 32 + lq * 8 + 2 * j;
        bu[j] = pk2bf(xf[c][rl], xf[c + 1][rl]);
      }
    }
    fx4 acc[4];
#pragma unroll
    for (int m = 0; m < 4; ++m) { acc[m][0]=0.f; acc[m][1]=0.f; acc[m][2]=0.f; acc[m][3]=0.f; }
#pragma unroll
    for (int m = 0; m < 4; ++m) {
#pragma unroll
      for (int ks = 0; ks < 2; ++ks) {
        bhalf8 a = *reinterpret_cast<const bhalf8*>(Wi + (m * 16 + cl) * 64 + ks * 32 + lq * 8);
        acc[m] = __builtin_amdgcn_mfma_f32_16x16x32_bf16(a, bfr[ks], acc[m], 0, 0, 0);
      }
    }
    if (p < P_) {
#pragma unroll
      for (int m = 0; m < 4; ++m) {
        uint2 d;
        d.x = pk2bf(acc[m][0] + pkv[m].x, acc[m][1] + pkv[m].y);
        d.y = pk2bf(acc[m][2] + pkv[m].z, acc[m][3] + pkv[m].w);
        *reinterpret_cast<uint2*>(qk2 + ((size_t)(n * 4 + m) * PT_ + p) * 16 + lq * 4) = d;
      }
    }
  }
}

// k1b: att partial GEMM; block=(ns, kq): K quadrant of 1600. Writes fp32 partials.
__global__ __launch_bounds__(256) void k1b(
    const unsigned short* __restrict__ qk2,
    float* __restrict__ pws)
{
  const int ns = blockIdx.x;
  const int kq = blockIdx.y;
  const int n = ns >> 1, s = ns & 1;
  const int tid = threadIdx.x;
  const int w = tid >> 6;
  const int l = tid & 63;
  const int cl = l & 15;
  const int lq = l >> 4;

  const unsigned short* qb = qk2 + (size_t)(n * 4 + s) * PT_ * 16;
  const unsigned short* kb = qk2 + (size_t)(n * 4 + 2 + s) * PT_ * 16;
  const int ci0 = (lq & 1) * 8;
  const int tof = lq >> 1;

  fx4 acc[2][2];
#pragma unroll
  for (int a1 = 0; a1 < 2; ++a1)
#pragma unroll
    for (int a2 = 0; a2 < 2; ++a2) { acc[a1][a2][0]=0.f; acc[a1][a2][1]=0.f; acc[a1][a2][2]=0.f; acc[a1][a2][3]=0.f; }

  for (int c = kq * 50 + w; c < kq * 50 + 50; c += 4) {
    const int t = c * 2 + tof;
    const size_t ro = ((size_t)t * 27) * 16 + ci0;
    bhalf8 aq0 = *reinterpret_cast<const bhalf8*>(qb + ro + (size_t)cl * 16);
    bhalf8 aq1 = *reinterpret_cast<const bhalf8*>(qb + ro + (size_t)(16 + cl) * 16);
    bhalf8 bk0 = *reinterpret_cast<const bhalf8*>(kb + ro + (size_t)cl * 16);
    bhalf8 bk1 = *reinterpret_cast<const bhalf8*>(kb + ro + (size_t)(16 + cl) * 16);
    acc[0][0] = __builtin_amdgcn_mfma_f32_16x16x32_bf16(aq0, bk0, acc[0][0], 0, 0, 0);
    acc[0][1] = __builtin_amdgcn_mfma_f32_16x16x32_bf16(aq0, bk1, acc[0][1], 0, 0, 0);
    acc[1][0] = __builtin_amdgcn_mfma_f32_16x16x32_bf16(aq1, bk0, acc[1][0], 0, 0, 0);
    acc[1][1] = __builtin_amdgcn_mfma_f32_16x16x32_bf16(aq1, bk1, acc[1][1], 0, 0, 0);
  }

  __shared__ float red[4][4][4][64];
#pragma unroll
  for (int mt = 0; mt < 2; ++mt)
#pragma unroll
    for (int nt = 0; nt < 2; ++nt)
#pragma unroll
      for (int r = 0; r < 4; ++r)
        red[w][mt * 2 + nt][r][l] = acc[mt][nt][r];
  __syncthreads();

  const int mt = w >> 1, nt = w & 1;
  const int v = nt * 16 + cl;
  float4 o;
  float* op = reinterpret_cast<float*>(&o);
#pragma unroll
  for (int r = 0; r < 4; ++r)
    op[r] = red[0][w][r][l] + red[1][w][r][l] + red[2][w][r][l] + red[3][w][r][l];
  *reinterpret_cast<float4*>(pws + ((size_t)kq * 64 + ns) * 1024 + v * 32 + mt * 16 + lq * 4) = o;
}

// k1c: reduce 4 K-quadrants + tanh finalize -> attT[ns][v32][u32] bf16 (zero-padded)
__global__ __launch_bounds__(256) void k1c(
    const float* __restrict__ pws,
    const float* __restrict__ alphas, const float* __restrict__ att0,
    unsigned short* __restrict__ attT)
{
  int idx = blockIdx.x * 256 + threadIdx.x;
  int ns = idx >> 10, j = idx & 1023;
  int v = j >> 5, u = j & 31;
  int s = ns & 1;
  float sum = pws[idx] + pws[65536 + idx] + pws[131072 + idx] + pws[196608 + idx];
  float val = 0.f;
  if (u < V_ && v < V_)
    val = tanhf(sum * (1.0f / 6400.0f)) * alphas[s] + att0[(s * V_ + u) * V_ + v];
  attT[idx] = f2bf(val);
}

// kz4b: FUSED x.att -> Wout -> bn1/res/lrelu -> Wff -> bn2/res/lrelu -> h2T
// 512 threads, 4 t per block. Z-phase: wave = (t, m-half), both s per wave.
__global__ __launch_bounds__(512) void kz4b(
    const float* __restrict__ x,
    const unsigned short* __restrict__ attT,
    const unsigned short* __restrict__ Wb,
    const float* __restrict__ cst,
    unsigned short* __restrict__ h2Tg)
{
  const int n = blockIdx.x;
  const int t0 = blockIdx.y * 4;
  const int pbase = t0 * 27;
  const int tid = threadIdx.x;
  const int w = tid >> 6;
  const int l = tid & 63;
  const int cl = l & 15;
  const int lq = l >> 4;

  __shared__ __align__(16) char zstg[32768];
  __shared__ __align__(16) char wout[16384];
  __shared__ __align__(16) char wffl[8192];
  __shared__ short h1t[128 * 64];
  __shared__ float clds[256];
  if (tid < 256) clds[tid] = cst[tid];

  for (int i = tid; i < 1024; i += 512) {
    int r = i >> 4, ch = i & 15;
    uint4 d = *reinterpret_cast<const uint4*>(Wb + r * 128 + ch * 8);
    *reinterpret_cast<uint4*>(wout + r * 256 + ((ch * 16) ^ ((r & 7) << 4))) = d;
  }
  for (int i = tid; i < 512; i += 512) {
    int r = i >> 3, ch = i & 7;
    uint4 d = *reinterpret_cast<const uint4*>(Wb + 8192 + r * 64 + ch * 8);
    *reinterpret_cast<uint4*>(wffl + r * 128 + ((ch * 16) ^ ((r & 7) << 4))) = d;
  }
  {
    uint4 z; z.x = 0; z.y = 0; z.z = 0; z.w = 0;
    for (int i = tid; i < 320; i += 512)
      *reinterpret_cast<uint4*>(zstg + 108 * 256 + i * 16) = z;
  }

  // ---- Z phase ----
  {
    const int th = w >> 1;
    const int mh = w & 1;
    const int t = t0 + th;
    bhalf8 batt[2][2];
#pragma unroll
    for (int s = 0; s < 2; ++s)
#pragma unroll
      for (int vt = 0; vt < 2; ++vt)
        batt[s][vt] = *reinterpret_cast<const bhalf8*>(
            attT + ((size_t)(n * 2 + s) * 32 + vt * 16 + cl) * 32 + lq * 8);
    bhalf8 ax[2];
    if (t * 27 + 31 < P_) {
#pragma unroll
      for (int mi = 0; mi < 2; ++mi) {
        const int m = mh * 2 + mi;
        const float* base = x + (size_t)(n * C_ + m * 16 + cl) * P_ + t * 27 + lq * 8;
        float4 f0 = *reinterpret_cast<const float4*>(base);
        float4 f1 = *reinterpret_cast<const float4*>(base + 4);
        unsigned* au = reinterpret_cast<unsigned*>(&ax[mi]);
        au[0] = pk2bf(f0.x, f0.y);
        au[1] = pk2bf(f0.z, f0.w);
        au[2] = pk2bf(f1.x, f1.y);
        au[3] = pk2bf(f1.z, f1.w);
      }
    } else {
#pragma unroll
      for (int mi = 0; mi < 2; ++mi) {
        const int m = mh * 2 + mi;
        const float* xr = x + (size_t)(n * C_ + m * 16 + cl) * P_;
#pragma unroll
        for (int j = 0; j < 8; ++j) {
          int idx = t * 27 + lq * 8 + j;
          idx = (idx < P_) ? idx : (P_ - 1);
          ax[mi][j] = (short)f2bf(xr[idx]);
        }
      }
    }
#pragma unroll
    for (int s = 0; s < 2; ++s) {
#pragma unroll
      for (int vt = 0; vt < 2; ++vt) {
        const int v = vt * 16 + cl;
#pragma unroll
        for (int mi = 0; mi < 2; ++mi) {
          const int m = mh * 2 + mi;
          fx4 z; z[0] = 0.f; z[1] = 0.f; z[2] = 0.f; z[3] = 0.f;
          fx4 dacc = __builtin_amdgcn_mfma_f32_16x16x32_bf16(ax[mi], batt[s][vt], z, 0, 0, 0);
          if (v < V_) {
            uint2 d;
            d.x = pk2bf(dacc[0], dacc[1]);
            d.y = pk2bf(dacc[2], dacc[3]);
            int row = th * 27 + v;
            int byteoff = row * 256 + (((s * 64 + m * 16 + lq * 4) * 2) ^ ((row & 7) << 4));
            *reinterpret_cast<uint2*>(zstg + byteoff) = d;
          }
        }
      }
    }
  }
  __syncthreads();

  // ---- phase3: y3 = Wout(64x128) . Z ----
  const int rl = w * 16 + cl;
  const int pidx = pbase + ((rl < 108) ? rl : 107);
  const int swz = (cl & 7) << 4;
  bhalf8 bfr[4];
#pragma unroll
  for (int ks = 0; ks < 4; ++ks)
    bfr[ks] = *reinterpret_cast<const bhalf8*>(zstg + rl * 256 + ((ks * 64 + lq * 16) ^ ((rl & 7) << 4)));
  fx4 acc[4];
#pragma unroll
  for (int m = 0; m < 4; ++m) { acc[m][0]=0.f; acc[m][1]=0.f; acc[m][2]=0.f; acc[m][3]=0.f; }
#pragma unroll
  for (int m = 0; m < 4; ++m) {
    const int row = m * 16 + cl;
#pragma unroll
    for (int ks = 0; ks < 4; ++ks) {
      bhalf8 a = *reinterpret_cast<const bhalf8*>(wout + row * 256 + ((ks * 64 + lq * 16) ^ ((row & 7) << 4)));
      acc[m] = __builtin_amdgcn_mfma_f32_16x16x32_bf16(a, bfr[ks], acc[m], 0, 0, 0);
    }
  }

  float xres[4][4];
#pragma unroll
  for (int m = 0; m < 4; ++m) {
    float h[4];
#pragma unroll
    for (int r = 0; r < 4; ++r) {
      int o = m * 16 + lq * 4 + r;
      float xv = x[((size_t)(n * C_ + o)) * (size_t)P_ + pidx];
      xres[m][r] = xv;
      float hv = acc[m][r] * clds[o] + clds[64 + o] + xv;
      h[r] = (hv >= 0.f) ? hv : 0.1f * hv;
    }
    uint2 d;
    d.x = pk2bf(h[0], h[1]);
    d.y = pk2bf(h[2], h[3]);
    int byteoff = rl * 128 + ((m * 32 + lq * 8) ^ swz);
    *reinterpret_cast<uint2*>(reinterpret_cast<char*>(h1t) + byteoff) = d;
  }

  // ---- phase4: f = Wff(64x64) . H1 (wave-local rows) ----
  fx4 acc2[4];
#pragma unroll
  for (int m = 0; m < 4; ++m) { acc2[m][0]=0.f; acc2[m][1]=0.f; acc2[m][2]=0.f; acc2[m][3]=0.f; }
#pragma unroll
  for (int ks = 0; ks < 2; ++ks) {
    int byteoff = rl * 128 + ((ks * 64 + lq * 16) ^ swz);
    bhalf8 b = *reinterpret_cast<const bhalf8*>(reinterpret_cast<char*>(h1t) + byteoff);
#pragma unroll
    for (int m = 0; m < 4; ++m) {
      const int row = m * 16 + cl;
      bhalf8 a = *reinterpret_cast<const bhalf8*>(wffl + row * 128 + ((ks * 64 + lq * 16) ^ ((row & 7) << 4)));
      acc2[m] = __builtin_amdgcn_mfma_f32_16x16x32_bf16(a, b, acc2[m], 0, 0, 0);
    }
  }

#pragma unroll
  for (int m = 0; m < 4; ++m) {
    float h[4];
#pragma unroll
    for (int r = 0; r < 4; ++r) {
      int o = m * 16 + lq * 4 + r;
      float hv = acc2[m][r] * clds[128 + o] + clds[192 + o] + xres[m][r];
      h[r] = (hv >= 0.f) ? hv : 0.1f * hv;
    }
    uint2 d;
    d.x = pk2bf(h[0], h[1]);
    d.y = pk2bf(h[2], h[3]);
    int byteoff = rl * 128 + ((m * 32 + lq * 8) ^ swz);
    *reinterpret_cast<uint2*>(reinterpret_cast<char*>(h1t) + byteoff) = d;
  }
  __syncthreads();

  {
    int row = tid >> 2, ch = tid & 3;
    if (row < 108) {
      int sw = (row & 7) << 4;
      uint4 d0 = *reinterpret_cast<uint4*>(reinterpret_cast<char*>(h1t) + row * 128 + (((2 * ch) * 16) ^ sw));
      uint4 d1 = *reinterpret_cast<uint4*>(reinterpret_cast<char*>(h1t) + row * 128 + (((2 * ch + 1) * 16) ^ sw));
      char* dst = reinterpret_cast<char*>(h2Tg) + ((size_t)n * HROWS + HGUARD + pbase + row) * 128 + ch * 32;
      *reinterpret_cast<uint4*>(dst) = d0;
      *reinterpret_cast<uint4*>(dst + 16) = d1;
    }
  }
}

// k4c: LDS-staged temporal conv K=192 MFMA GEMM + bn3/res/lrelu -> out
// 512 threads, 128-p tile (+/-32 halo).
__global__ __launch_bounds__(512) void k4c(
    const unsigned short* __restrict__ h2Tg,
    const unsigned short* __restrict__ Wtb,
    const float* __restrict__ cst,
    float* __restrict__ out)
{
  const int n = blockIdx.x;
  const int p0 = blockIdx.y * 128;
  const int tid = threadIdx.x;
  const int w = tid >> 6;
  const int l = tid & 63;
  const int cl = l & 15;
  const int lq = l >> 4;
  const int p = p0 + w * 16 + cl;

  __shared__ __align__(16) char hst[24576];
  __shared__ __align__(16) char wst[24576];
  __shared__ float clds[128];
  if (tid < 128) clds[tid] = cst[256 + tid];

  const unsigned short* hbase = h2Tg + ((size_t)n * HROWS + HGUARD + p0 - 32) * 64;
  for (int i = tid; i < 1536; i += 512) {
    int r = i >> 3, ch = i & 7;
    uint4 d = *reinterpret_cast<const uint4*>(hbase + (size_t)r * 64 + ch * 8);
    *reinterpret_cast<uint4*>(hst + r * 128 + ((ch * 16) ^ ((r & 7) << 4))) = d;
  }
  for (int i = tid; i < 1536; i += 512) {
    int r = i / 24, ch = i - r * 24;
    uint4 d = *reinterpret_cast<const uint4*>(Wtb + r * 192 + ch * 8);
    *reinterpret_cast<uint4*>(wst + r * 384 + ((ch * 16) ^ ((r & 7) << 4))) = d;
  }
  __syncthreads();

  const int rl = 32 + w * 16 + cl;
  bhalf8 bfr[6];
#pragma unroll
  for (int ks = 0; ks < 6; ++ks) {
    int k0 = ks * 32 + lq * 8;
    int dt = k0 >> 6;
    int i0 = k0 & 63;
    int rr = rl + (dt - 1) * 27;
    bfr[ks] = *reinterpret_cast<const bhalf8*>(hst + rr * 128 + ((2 * i0) ^ ((rr & 7) << 4)));
  }
  fx4 acc[4];
#pragma unroll
  for (int m = 0; m < 4; ++m) { acc[m][0]=0.f; acc[m][1]=0.f; acc[m][2]=0.f; acc[m][3]=0.f; }
#pragma unroll
  for (int m = 0; m < 4; ++m) {
    const int row = m * 16 + cl;
#pragma unroll
    for (int ks = 0; ks < 6; ++ks) {
      bhalf8 a = *reinterpret_cast<const bhalf8*>(wst + row * 384 + ((ks * 64 + lq * 16) ^ ((row & 7) << 4)));
      acc[m] = __builtin_amdgcn_mfma_f32_16x16x32_bf16(a, bfr[ks], acc[m], 0, 0, 0);
    }
  }
  if (p < P_) {
#pragma unroll
    for (int m = 0; m < 4; ++m) {
      uint2 hr = *reinterpret_cast<uint2*>(hst + rl * 128 + (((m * 16 + lq * 4) * 2) ^ ((rl & 7) << 4)));
      float hc[4];
      hc[0] = bf2f((unsigned short)(hr.x & 0xffff));
      hc[1] = bf2f((unsigned short)(hr.x >> 16));
      hc[2] = bf2f((unsigned short)(hr.y & 0xffff));
      hc[3] = bf2f((unsigned short)(hr.y >> 16));
#pragma unroll
      for (int r = 0; r < 4; ++r) {
        int o = m * 16 + lq * 4 + r;
        float val = acc[m][r] * clds[o] + clds[64 + o] + hc[r];
        val = (val >= 0.f) ? val : 0.1f * val;
        out[((size_t)(n * CO_ + o)) * (size_t)P_ + p] = val;
      }
    }
  }
}

// ================= fallback path =================
__global__ __launch_bounds__(256) void k1_qk_partial(
    const float* __restrict__ x, const float* __restrict__ pe,
    const float* __restrict__ w_in, const float* __restrict__ b_in,
    float* __restrict__ partial)
{
  const int n = blockIdx.x;
  const int chunk = blockIdx.y;
  const int tid = threadIdx.x;
  __shared__ float ylds[C_][28];
  __shared__ float qlds[C_][28];
  __shared__ float wlds[C_][65];
  for (int i = tid; i < C_ * C_; i += 256) wlds[i >> 6][i & 63] = w_in[i];
  float acc[6];
#pragma unroll
  for (int j = 0; j < 6; ++j) acc[j] = 0.f;
  const int t0 = chunk * TCHUNK;
  for (int tt = 0; tt < TCHUNK; ++tt) {
    const int t = t0 + tt;
    __syncthreads();
    for (int i = tid; i < C_ * V_; i += 256) {
      int c = i / V_, v = i - c * V_;
      ylds[c][v] = x[((size_t)(n * C_ + c) * T_ + t) * V_ + v] + pe[(c * T_ + t) * V_ + v];
    }
    __syncthreads();
    for (int i = tid; i < C_ * V_; i += 256) {
      int o = i / V_, v = i - o * V_;
      float s = b_in[o];
#pragma unroll
      for (int c = 0; c < C_; ++c) s += wlds[o][c] * ylds[c][v];
      qlds[o][v] = s;
    }
    __syncthreads();
#pragma unroll
    for (int j = 0; j < 6; ++j) {
      int i = tid + j * 256;
      if (i < ATT_N) {
        int s = i / 729, r = i - s * 729, u = r / 27, v = r - u * 27;
        float a = 0.f;
#pragma unroll
        for (int c = 0; c < CI_; ++c)
          a += qlds[s * CI_ + c][u] * qlds[S_ * CI_ + s * CI_ + c][v];
        acc[j] += a;
      }
    }
  }
  float* dst = partial + (size_t)(n * NCHUNK + chunk) * ATT_N;
#pragma unroll
  for (int j = 0; j < 6; ++j) {
    int i = tid + j * 256;
    if (i < ATT_N) dst[i] = acc[j];
  }
}

__global__ __launch_bounds__(256) void k2_att_fin(
    const float* __restrict__ partial, const float* __restrict__ alphas,
    const float* __restrict__ att0, float* __restrict__ att)
{
  int i = blockIdx.x * 256 + threadIdx.x;
  if (i >= N_ * ATT_N) return;
  int n = i / ATT_N, r = i - n * ATT_N;
  int s = r / 729;
  float a = 0.f;
  const float* p = partial + (size_t)n * NCHUNK * ATT_N + r;
  for (int ch = 0; ch < NCHUNK; ++ch) a += p[(size_t)ch * ATT_N];
  a = tanhf(a * (1.0f / (CI_ * (float)T_))) * alphas[s] + att0[r];
  att[i] = a;
}

__global__ __launch_bounds__(256) void k3a(
    const float* __restrict__ x, const float* __restrict__ att,
    const float* __restrict__ w_out, const float* __restrict__ b_out,
    const float* __restrict__ bn1_g, const float* __restrict__ bn1_b,
    const float* __restrict__ bn1_m, const float* __restrict__ bn1_v,
    const float* __restrict__ w_ff, const float* __restrict__ b_ff,
    const float* __restrict__ bn2_g, const float* __restrict__ bn2_b,
    const float* __restrict__ bn2_m, const float* __restrict__ bn2_v,
    float* __restrict__ h2g)
{
  const int n = blockIdx.x;
  const int t0 = blockIdx.y * 2;
  const int tid = threadIdx.x;
  const int v = tid & 31;
  const int tloc = (tid >> 5) & 1;
  const int col = tid & 63;
  const int rg = __builtin_amdgcn_readfirstlane(tid >> 6);
  const int t = t0 + tloc;

  __shared__ float xlds[C_][64];
  __shared__ float zlds[S_ * C_][64];

  for (int i = tid; i < C_ * 64; i += 256) {
    int c = i >> 6, cl = i & 63, tl = cl >> 5, vv = cl & 31;
    xlds[c][cl] = (vv < V_) ? x[((size_t)(n * C_ + c) * T_ + t0 + tl) * V_ + vv] : 0.f;
  }
  float attreg[S_][V_];
  {
    const float* ab = att + (size_t)n * ATT_N + v;
#pragma unroll
    for (int s = 0; s < S_; ++s)
#pragma unroll
      for (int u = 0; u < V_; ++u)
        attreg[s][u] = (v < V_) ? ab[s * 729 + u * 27] : 0.f;
  }
  __syncthreads();
#pragma unroll 1
  for (int cc = 0; cc < 16; ++cc) {
    const int c = rg * 16 + cc;
    float xr[V_];
#pragma unroll
    for (int u = 0; u < V_; ++u) xr[u] = xlds[c][tloc * 32 + u];
    float a0 = 0.f, a1 = 0.f;
#pragma unroll
    for (int u = 0; u < V_; ++u) {
      a0 += xr[u] * attreg[0][u];
      a1 += xr[u] * attreg[1][u];
    }
    zlds[c][col] = a0;
    zlds[C_ + c][col] = a1;
  }
  __syncthreads();
  float acc[16];
#pragma unroll
  for (int oo = 0; oo < 16; ++oo) acc[oo] = 0.f;
#pragma unroll 1
  for (int kc = 0; kc < 4; ++kc) {
    float zk[32];
#pragma unroll
    for (int j = 0; j < 32; ++j) zk[j] = zlds[kc * 32 + j][col];
#pragma unroll
    for (int oo = 0; oo < 16; ++oo) {
      const float* wr = w_out + (rg * 16 + oo) * (S_ * C_) + kc * 32;
      float s = acc[oo];
#pragma unroll
      for (int j = 0; j < 32; ++j) s += wr[j] * zk[j];
      acc[oo] = s;
    }
  }
  float h1v[16];
#pragma unroll
  for (int oo = 0; oo < 16; ++oo) {
    const int o = rg * 16 + oo;
    float y3 = acc[oo] + b_out[o];
    float h = (y3 - bn1_m[o]) * (bn1_g[o] * rsqrtf(bn1_v[o] + 1e-5f)) + bn1_b[o]
              + xlds[o][col];
    h1v[oo] = (h >= 0.f) ? h : 0.1f * h;
  }
  __syncthreads();
#pragma unroll
  for (int oo = 0; oo < 16; ++oo) zlds[rg * 16 + oo][col] = h1v[oo];
  __syncthreads();
#pragma unroll
  for (int oo = 0; oo < 16; ++oo) acc[oo] = 0.f;
#pragma unroll 1
  for (int kc = 0; kc < 2; ++kc) {
    float zk[32];
#pragma unroll
    for (int j = 0; j < 32; ++j) zk[j] = zlds[kc * 32 + j][col];
#pragma unroll
    for (int oo = 0; oo < 16; ++oo) {
      const float* wr = w_ff + (rg * 16 + oo) * C_ + kc * 32;
      float s = acc[oo];
#pragma unroll
      for (int j = 0; j < 32; ++j) s += wr[j] * zk[j];
      acc[oo] = s;
    }
  }
  if (v < V_) {
#pragma unroll
    for (int oo = 0; oo < 16; ++oo) {
      const int o = rg * 16 + oo;
      float f = acc[oo] + b_ff[o];
      float h = (f - bn2_m[o]) * (bn2_g[o] * rsqrtf(bn2_v[o] + 1e-5f)) + bn2_b[o]
                + xlds[o][col];
      h2g[((size_t)(n * CO_ + o) * T_ + t) * V_ + v] = (h >= 0.f) ? h : 0.1f * h;
    }
  }
}

__global__ __launch_bounds__(256) void k3b(
    const float* __restrict__ h2g, const float* __restrict__ w_t,
    const float* __restrict__ b_t,
    const float* __restrict__ bn3_g, const float* __restrict__ bn3_b,
    const float* __restrict__ bn3_m, const float* __restrict__ bn3_v,
    float* __restrict__ out)
{
  const int n = blockIdx.x;
  const int t0 = blockIdx.y * 2;
  const int tid = threadIdx.x;
  const int v = tid & 31;
  const int tloc = (tid >> 5) & 1;
  const int rg = __builtin_amdgcn_readfirstlane(tid >> 6);
  const int t = t0 + tloc;

  __shared__ float hl[C_][4][32];

  for (int idx = tid; idx < C_ * 4 * 32; idx += 256) {
    int i = idx >> 7, r = idx & 127, sl = r >> 5, vv = r & 31;
    int tg = t0 - 1 + sl;
    hl[i][sl][vv] = (vv < V_ && tg >= 0 && tg < T_)
                    ? h2g[((size_t)(n * CO_ + i) * T_ + tg) * V_ + vv] : 0.f;
  }
  __syncthreads();

  float acc[16];
#pragma unroll
  for (int oo = 0; oo < 16; ++oo) acc[oo] = 0.f;
#pragma unroll 1
  for (int ic = 0; ic < 4; ++ic) {
    float h[16][3];
#pragma unroll
    for (int ii = 0; ii < 16; ++ii) {
      h[ii][0] = hl[ic * 16 + ii][tloc][v];
      h[ii][1] = hl[ic * 16 + ii][tloc + 1][v];
      h[ii][2] = hl[ic * 16 + ii][tloc + 2][v];
    }
#pragma unroll
    for (int oo = 0; oo < 16; ++oo) {
      const float* wr = w_t + ((size_t)(rg * 16 + oo) * C_ + ic * 16) * 3;
      float s = acc[oo];
#pragma unroll
      for (int ii = 0; ii < 16; ++ii) {
        s += wr[ii * 3 + 0] * h[ii][0]
           + wr[ii * 3 + 1] * h[ii][1]
           + wr[ii * 3 + 2] * h[ii][2];
      }
      acc[oo] = s;
    }
  }
  if (v < V_) {
#pragma unroll
    for (int oo = 0; oo < 16; ++oo) {
      const int o = rg * 16 + oo;
      float zv = acc[oo] + b_t[o];
      float r = (zv - bn3_m[o]) * (bn3_g[o] * rsqrtf(bn3_v[o] + 1e-5f)) + bn3_b[o]
                + hl[o][tloc + 1][v];
      out[((size_t)(n * CO_ + o) * T_ + t) * V_ + v] = (r >= 0.f) ? r : 0.1f * r;
    }
  }
}

extern "C" void kernel_launch(void* const* d_in, const int* in_sizes, int n_in,
                              void* d_out, int out_size, void* d_ws, size_t ws_size,
                              hipStream_t stream)
{
  (void)in_sizes; (void)n_in; (void)out_size;
  const float* x      = (const float*)d_in[0];
  const float* pe     = (const float*)d_in[1];
  const float* w_in   = (const float*)d_in[2];
  const float* b_in   = (const float*)d_in[3];
  const float* alphas = (const float*)d_in[4];
  const float* att0   = (const float*)d_in[5];
  const float* w_out  = (const float*)d_in[6];
  const float* b_out  = (const float*)d_in[7];
  const float* bn1_g  = (const float*)d_in[8];
  const float* bn1_b  = (const float*)d_in[9];
  const float* bn1_m  = (const float*)d_in[10];
  const float* bn1_v  = (const float*)d_in[11];
  const float* w_ff   = (const float*)d_in[12];
  const float* b_ff   = (const float*)d_in[13];
  const float* bn2_g  = (const float*)d_in[14];
  const float* bn2_b  = (const float*)d_in[15];
  const float* bn2_m  = (const float*)d_in[16];
  const float* bn2_v  = (const float*)d_in[17];
  const float* w_t    = (const float*)d_in[18];
  const float* b_t    = (const float*)d_in[19];
  const float* bn3_g  = (const float*)d_in[20];
  const float* bn3_b  = (const float*)d_in[21];
  const float* bn3_m  = (const float*)d_in[22];
  const float* bn3_v  = (const float*)d_in[23];
  float* out = (float*)d_out;

  char* ws = (char*)d_ws;
  unsigned short* Wb   = (unsigned short*)(ws);              // 57,344 B
  float*          cst  = (float*)(ws + 57344);               // 1,792 B
  unsigned short* attT = (unsigned short*)(ws + 59136);      // 131,072 B
  float*          pws  = (float*)(ws + 190208);              // 1,048,576 B
  float*          qkpe = (float*)(ws + 1238784);             // 2,768,896 B
  unsigned short* qk2  = (unsigned short*)(ws + 4007680);    // 44,302,336 B
  unsigned short* h2T  = (unsigned short*)(ws + 48310016);   // 44,826,624 B
  const size_t need_mfma = 93136640;
  const size_t need_old  = ((size_t)N_ * NCHUNK * ATT_N + (size_t)N_ * ATT_N
                            + (size_t)N_ * CO_ * T_ * V_) * sizeof(float);

  if (ws_size >= need_mfma) {
    kprep<<<64, 256, 0, stream>>>(w_out, w_ff, w_t, w_in, b_out, b_ff, b_t, b_in,
        bn1_g, bn1_b, bn1_m, bn1_v, bn2_g, bn2_b, bn2_m, bn2_v,
        bn3_g, bn3_b, bn3_m, bn3_v, Wb, cst, h2T);
    kpe<<<QTILES, 256, 0, stream>>>(pe, Wb, cst, qkpe);
    k1a2<<<dim3(N_, QTILES), 256, 0, stream>>>(x, Wb, qkpe, qk2);
    k1b<<<dim3(64, 4), 256, 0, stream>>>(qk2, pws);
    k1c<<<256, 256, 0, stream>>>(pws, alphas, att0, attT);
    kz4b<<<dim3(N_, T_ / 4), 512, 0, stream>>>(x, attT, Wb, cst, h2T);
    k4c<<<dim3(N_, QTILES), 512, 0, stream>>>(h2T, Wb + 12288, cst, out);
  } else if (ws_size >= need_old) {
    float* partial = (float*)ws;
    float* att     = partial + (size_t)N_ * NCHUNK * ATT_N;
    float* h2g     = att + (size_t)N_ * ATT_N;
    k1_qk_partial<<<dim3(N_, NCHUNK), 256, 0, stream>>>(x, pe, w_in, b_in, partial);
    k2_att_fin<<<(N_ * ATT_N + 255) / 256, 256, 0, stream>>>(partial, alphas, att0, att);
    k3a<<<dim3(N_, T_ / 2), 256, 0, stream>>>(x, att,
        w_out, b_out, bn1_g, bn1_b, bn1_m, bn1_v,
        w_ff, b_ff, bn2_g, bn2_b, bn2_m, bn2_v, h2g);
    k3b<<<dim3(N_, T_ / 2), 256, 0, stream>>>(h2g, w_t, b_t,
        bn3_g, bn3_b, bn3_m, bn3_v, out);
  }
}

// Round 18
// 142.834 us; speedup vs baseline: 1.1101x; 1.1101x over previous
//
#include <hip/hip_runtime.h>

#define N_ 32
#define C_ 64
#define T_ 400
#define V_ 27
#define S_ 2
#define CI_ 16
#define CO_ 64
#define TCHUNK 8
#define NCHUNK 50
#define ATT_N 1458           // S_*V_*V_
#define P_ 10800             // T_*V_
#define PT_ 10816            // 169*64
#define QTILES 85            // ceil(P_/128)
#define HGUARD 32
#define HROWS 10944          // HGUARD + P_ + 112

typedef short bhalf8 __attribute__((ext_vector_type(8)));
typedef float fx4 __attribute__((ext_vector_type(4)));

static __device__ inline unsigned short f2bf(float f) {
  return __builtin_bit_cast(unsigned short, (__bf16)f);
}
static __device__ inline unsigned pk2bf(float lo, float hi) {
  return (unsigned)f2bf(lo) | ((unsigned)f2bf(hi) << 16);
}
static __device__ inline float bf2f(unsigned short h) {
  unsigned u = ((unsigned)h) << 16;
  return __builtin_bit_cast(float, u);
}

// ================= MFMA path =================

// kprep: bf16 weights (Wout|Wff|Wt|Wi), fused bn consts + b_in, zero h2T guards
__global__ __launch_bounds__(256) void kprep(
    const float* __restrict__ w_out, const float* __restrict__ w_ff,
    const float* __restrict__ w_t, const float* __restrict__ w_in,
    const float* __restrict__ b_out, const float* __restrict__ b_ff,
    const float* __restrict__ b_t, const float* __restrict__ b_in,
    const float* __restrict__ bn1_g, const float* __restrict__ bn1_b,
    const float* __restrict__ bn1_m, const float* __restrict__ bn1_v,
    const float* __restrict__ bn2_g, const float* __restrict__ bn2_b,
    const float* __restrict__ bn2_m, const float* __restrict__ bn2_v,
    const float* __restrict__ bn3_g, const float* __restrict__ bn3_b,
    const float* __restrict__ bn3_m, const float* __restrict__ bn3_v,
    unsigned short* __restrict__ Wb, float* __restrict__ cst,
    unsigned short* __restrict__ h2Tg)
{
  const int tid = threadIdx.x;
  const int bid = blockIdx.x;
  uint4 z; z.x = 0; z.y = 0; z.z = 0; z.w = 0;
  for (int i = bid * 256 + tid; i < N_ * 1152; i += 64 * 256) {
    int n = i / 1152, r = i - n * 1152;
    size_t off = (r < 256) ? (size_t)r * 8 : (size_t)10832 * 64 + (size_t)(r - 256) * 8;
    *reinterpret_cast<uint4*>(h2Tg + (size_t)n * HROWS * 64 + off) = z;
  }
  if (bid != 0) return;
  for (int i = tid; i < 8192; i += 256) Wb[i] = f2bf(w_out[i]);
  for (int i = tid; i < 4096; i += 256) Wb[8192 + i] = f2bf(w_ff[i]);
  for (int i = tid; i < 12288; i += 256) {
    int o = i / 192, r = i - o * 192, dt = r >> 6, ic = r & 63;
    Wb[12288 + i] = f2bf(w_t[(size_t)(o * 64 + ic) * 3 + dt]);
  }
  for (int i = tid; i < 4096; i += 256) Wb[24576 + i] = f2bf(w_in[i]);
  if (tid < 64) {
    int o = tid;
    float a1 = bn1_g[o] * rsqrtf(bn1_v[o] + 1e-5f);
    cst[o] = a1;
    cst[64 + o] = (b_out[o] - bn1_m[o]) * a1 + bn1_b[o];
    float a2 = bn2_g[o] * rsqrtf(bn2_v[o] + 1e-5f);
    cst[128 + o] = a2;
    cst[192 + o] = (b_ff[o] - bn2_m[o]) * a2 + bn2_b[o];
    float a3 = bn3_g[o] * rsqrtf(bn3_v[o] + 1e-5f);
    cst[256 + o] = a3;
    cst[320 + o] = (b_t[o] - bn3_m[o]) * a3 + bn3_b[o];
    cst[384 + o] = b_in[o];
  }
}

// k1a2: fused (x+pe) stage (bf16 LDS, batched loads) + qk = Wi . y -> qk2
__global__ __launch_bounds__(256) void k1a2(
    const float* __restrict__ x, const float* __restrict__ pe,
    const unsigned short* __restrict__ Wb,
    const float* __restrict__ cst,
    unsigned short* __restrict__ qk2)
{
  const int n = blockIdx.x;
  const int p0 = blockIdx.y * 128;
  const int tid = threadIdx.x;
  const int w = tid >> 6;
  const int l = tid & 63;
  const int cl = l & 15;
  const int lq = l >> 4;

  __shared__ unsigned short xlb[64][132];   // bf16 tile, row stride 264B
  __shared__ float clds[64];
  if (tid < 64) clds[tid] = cst[384 + tid];

  const int c_s = tid >> 5;                 // staging row 0..7 (+8 per group)
  const int c4_s = tid & 31;                // 4-float chunk within 128p
  const int pp_s = p0 + c4_s * 4;

  if (p0 + 128 <= P_) {
#pragma unroll
    for (int half = 0; half < 2; ++half) {
      float4 xa0, xa1, xa2, xa3, pa0, pa1, pa2, pa3;
      const int cb = half * 32 + c_s;
      {
        const float* xb = x + (size_t)(n * C_ + cb) * P_ + pp_s;
        const float* pb = pe + (size_t)cb * P_ + pp_s;
        xa0 = *reinterpret_cast<const float4*>(xb);
        pa0 = *reinterpret_cast<const float4*>(pb);
        xa1 = *reinterpret_cast<const float4*>(xb + (size_t)8 * P_);
        pa1 = *reinterpret_cast<const float4*>(pb + (size_t)8 * P_);
        xa2 = *reinterpret_cast<const float4*>(xb + (size_t)16 * P_);
        pa2 = *reinterpret_cast<const float4*>(pb + (size_t)16 * P_);
        xa3 = *reinterpret_cast<const float4*>(xb + (size_t)24 * P_);
        pa3 = *reinterpret_cast<const float4*>(pb + (size_t)24 * P_);
      }
      uint2 d;
      d.x = pk2bf(xa0.x + pa0.x, xa0.y + pa0.y);
      d.y = pk2bf(xa0.z + pa0.z, xa0.w + pa0.w);
      *reinterpret_cast<uint2*>(&xlb[cb][c4_s * 4]) = d;
      d.x = pk2bf(xa1.x + pa1.x, xa1.y + pa1.y);
      d.y = pk2bf(xa1.z + pa1.z, xa1.w + pa1.w);
      *reinterpret_cast<uint2*>(&xlb[cb + 8][c4_s * 4]) = d;
      d.x = pk2bf(xa2.x + pa2.x, xa2.y + pa2.y);
      d.y = pk2bf(xa2.z + pa2.z, xa2.w + pa2.w);
      *reinterpret_cast<uint2*>(&xlb[cb + 16][c4_s * 4]) = d;
      d.x = pk2bf(xa3.x + pa3.x, xa3.y + pa3.y);
      d.y = pk2bf(xa3.z + pa3.z, xa3.w + pa3.w);
      *reinterpret_cast<uint2*>(&xlb[cb + 24][c4_s * 4]) = d;
    }
  } else {
#pragma unroll
    for (int k = 0; k < 8; ++k) {
      int c = k * 8 + c_s;
      const float* xr = x + (size_t)(n * C_ + c) * P_;
      const float* pr = pe + (size_t)c * P_;
      float v0 = (pp_s + 0 < P_) ? (xr[pp_s + 0] + pr[pp_s + 0]) : 0.f;
      float v1 = (pp_s + 1 < P_) ? (xr[pp_s + 1] + pr[pp_s + 1]) : 0.f;
      float v2 = (pp_s + 2 < P_) ? (xr[pp_s + 2] + pr[pp_s + 2]) : 0.f;
      float v3 = (pp_s + 3 < P_) ? (xr[pp_s + 3] + pr[pp_s + 3]) : 0.f;
      uint2 d;
      d.x = pk2bf(v0, v1);
      d.y = pk2bf(v2, v3);
      *reinterpret_cast<uint2*>(&xlb[c][c4_s * 4]) = d;
    }
  }
  __syncthreads();

  const unsigned short* Wi = Wb + 24576;
#pragma unroll
  for (int h = 0; h < 2; ++h) {
    const int rl = h * 64 + w * 16 + cl;
    const int p = p0 + rl;
    bhalf8 bfr[2];
#pragma unroll
    for (int ks = 0; ks < 2; ++ks) {
      unsigned* bu = reinterpret_cast<unsigned*>(&bfr[ks]);
#pragma unroll
      for (int j = 0; j < 4; ++j) {
        int c = ks * 32 + lq * 8 + 2 * j;
        bu[j] = (unsigned)xlb[c][rl] | ((unsigned)xlb[c + 1][rl] << 16);
      }
    }
    fx4 acc[4];
#pragma unroll
    for (int m = 0; m < 4; ++m) { acc[m][0]=0.f; acc[m][1]=0.f; acc[m][2]=0.f; acc[m][3]=0.f; }
#pragma unroll
    for (int m = 0; m < 4; ++m) {
#pragma unroll
      for (int ks = 0; ks < 2; ++ks) {
        bhalf8 a = *reinterpret_cast<const bhalf8*>(Wi + (m * 16 + cl) * 64 + ks * 32 + lq * 8);
        acc[m] = __builtin_amdgcn_mfma_f32_16x16x32_bf16(a, bfr[ks], acc[m], 0, 0, 0);
      }
    }
    if (p < P_) {
#pragma unroll
      for (int m = 0; m < 4; ++m) {
        uint2 d;
        d.x = pk2bf(acc[m][0] + clds[m * 16 + lq * 4 + 0], acc[m][1] + clds[m * 16 + lq * 4 + 1]);
        d.y = pk2bf(acc[m][2] + clds[m * 16 + lq * 4 + 2], acc[m][3] + clds[m * 16 + lq * 4 + 3]);
        *reinterpret_cast<uint2*>(qk2 + ((size_t)(n * 4 + m) * PT_ + p) * 16 + lq * 4) = d;
      }
    }
  }
}

// k1b: att partial GEMM; block=(ns, kq): K quadrant of 1600. Writes fp32 partials.
__global__ __launch_bounds__(256) void k1b(
    const unsigned short* __restrict__ qk2,
    float* __restrict__ pws)
{
  const int ns = blockIdx.x;
  const int kq = blockIdx.y;
  const int n = ns >> 1, s = ns & 1;
  const int tid = threadIdx.x;
  const int w = tid >> 6;
  const int l = tid & 63;
  const int cl = l & 15;
  const int lq = l >> 4;

  const unsigned short* qb = qk2 + (size_t)(n * 4 + s) * PT_ * 16;
  const unsigned short* kb = qk2 + (size_t)(n * 4 + 2 + s) * PT_ * 16;
  const int ci0 = (lq & 1) * 8;
  const int tof = lq >> 1;

  fx4 acc[2][2];
#pragma unroll
  for (int a1 = 0; a1 < 2; ++a1)
#pragma unroll
    for (int a2 = 0; a2 < 2; ++a2) { acc[a1][a2][0]=0.f; acc[a1][a2][1]=0.f; acc[a1][a2][2]=0.f; acc[a1][a2][3]=0.f; }

  for (int c = kq * 50 + w; c < kq * 50 + 50; c += 4) {
    const int t = c * 2 + tof;
    const size_t ro = ((size_t)t * 27) * 16 + ci0;
    bhalf8 aq0 = *reinterpret_cast<const bhalf8*>(qb + ro + (size_t)cl * 16);
    bhalf8 aq1 = *reinterpret_cast<const bhalf8*>(qb + ro + (size_t)(16 + cl) * 16);
    bhalf8 bk0 = *reinterpret_cast<const bhalf8*>(kb + ro + (size_t)cl * 16);
    bhalf8 bk1 = *reinterpret_cast<const bhalf8*>(kb + ro + (size_t)(16 + cl) * 16);
    acc[0][0] = __builtin_amdgcn_mfma_f32_16x16x32_bf16(aq0, bk0, acc[0][0], 0, 0, 0);
    acc[0][1] = __builtin_amdgcn_mfma_f32_16x16x32_bf16(aq0, bk1, acc[0][1], 0, 0, 0);
    acc[1][0] = __builtin_amdgcn_mfma_f32_16x16x32_bf16(aq1, bk0, acc[1][0], 0, 0, 0);
    acc[1][1] = __builtin_amdgcn_mfma_f32_16x16x32_bf16(aq1, bk1, acc[1][1], 0, 0, 0);
  }

  __shared__ float red[4][4][4][64];
#pragma unroll
  for (int mt = 0; mt < 2; ++mt)
#pragma unroll
    for (int nt = 0; nt < 2; ++nt)
#pragma unroll
      for (int r = 0; r < 4; ++r)
        red[w][mt * 2 + nt][r][l] = acc[mt][nt][r];
  __syncthreads();

  const int mt = w >> 1, nt = w & 1;
  const int v = nt * 16 + cl;
  float4 o;
  float* op = reinterpret_cast<float*>(&o);
#pragma unroll
  for (int r = 0; r < 4; ++r)
    op[r] = red[0][w][r][l] + red[1][w][r][l] + red[2][w][r][l] + red[3][w][r][l];
  *reinterpret_cast<float4*>(pws + ((size_t)kq * 64 + ns) * 1024 + v * 32 + mt * 16 + lq * 4) = o;
}

// k1c: reduce 4 K-quadrants + tanh finalize -> attT[ns][v32][u32] bf16 (zero-padded)
__global__ __launch_bounds__(256) void k1c(
    const float* __restrict__ pws,
    const float* __restrict__ alphas, const float* __restrict__ att0,
    unsigned short* __restrict__ attT)
{
  int idx = blockIdx.x * 256 + threadIdx.x;
  int ns = idx >> 10, j = idx & 1023;
  int v = j >> 5, u = j & 31;
  int s = ns & 1;
  float sum = pws[idx] + pws[65536 + idx] + pws[131072 + idx] + pws[196608 + idx];
  float val = 0.f;
  if (u < V_ && v < V_)
    val = tanhf(sum * (1.0f / 6400.0f)) * alphas[s] + att0[(s * V_ + u) * V_ + v];
  attT[idx] = f2bf(val);
}

// kz4b: FUSED x.att -> Wout -> bn1/res/lrelu -> Wff -> bn2/res/lrelu -> h2T
// 512 threads, 4 t per block. Z-phase: wave = (t, m-half), both s per wave
// (dedups x loads/converts). H1/h2 stores packed as uint2.
__global__ __launch_bounds__(512) void kz4b(
    const float* __restrict__ x,
    const unsigned short* __restrict__ attT,
    const unsigned short* __restrict__ Wb,
    const float* __restrict__ cst,
    unsigned short* __restrict__ h2Tg)
{
  const int n = blockIdx.x;
  const int t0 = blockIdx.y * 4;
  const int pbase = t0 * 27;
  const int tid = threadIdx.x;
  const int w = tid >> 6;
  const int l = tid & 63;
  const int cl = l & 15;
  const int lq = l >> 4;

  __shared__ __align__(16) char zstg[32768];
  __shared__ __align__(16) char wout[16384];
  __shared__ __align__(16) char wffl[8192];
  __shared__ short h1t[128 * 64];
  __shared__ float clds[256];
  if (tid < 256) clds[tid] = cst[tid];

  for (int i = tid; i < 1024; i += 512) {
    int r = i >> 4, ch = i & 15;
    uint4 d = *reinterpret_cast<const uint4*>(Wb + r * 128 + ch * 8);
    *reinterpret_cast<uint4*>(wout + r * 256 + ((ch * 16) ^ ((r & 7) << 4))) = d;
  }
  for (int i = tid; i < 512; i += 512) {
    int r = i >> 3, ch = i & 7;
    uint4 d = *reinterpret_cast<const uint4*>(Wb + 8192 + r * 64 + ch * 8);
    *reinterpret_cast<uint4*>(wffl + r * 128 + ((ch * 16) ^ ((r & 7) << 4))) = d;
  }
  {
    uint4 z; z.x = 0; z.y = 0; z.z = 0; z.w = 0;
    for (int i = tid; i < 320; i += 512)
      *reinterpret_cast<uint4*>(zstg + 108 * 256 + i * 16) = z;
  }

  // ---- Z phase: wave w -> t = t0 + (w>>1), m in {2*(w&1), 2*(w&1)+1}, both s ----
  {
    const int th = w >> 1;
    const int mh = w & 1;
    const int t = t0 + th;
    bhalf8 batt[2][2];
#pragma unroll
    for (int s = 0; s < 2; ++s)
#pragma unroll
      for (int vt = 0; vt < 2; ++vt)
        batt[s][vt] = *reinterpret_cast<const bhalf8*>(
            attT + ((size_t)(n * 2 + s) * 32 + vt * 16 + cl) * 32 + lq * 8);
    bhalf8 ax[2];
    if (t * 27 + 31 < P_) {
#pragma unroll
      for (int mi = 0; mi < 2; ++mi) {
        const int m = mh * 2 + mi;
        const float* base = x + (size_t)(n * C_ + m * 16 + cl) * P_ + t * 27 + lq * 8;
        float4 f0 = *reinterpret_cast<const float4*>(base);
        float4 f1 = *reinterpret_cast<const float4*>(base + 4);
        unsigned* au = reinterpret_cast<unsigned*>(&ax[mi]);
        au[0] = pk2bf(f0.x, f0.y);
        au[1] = pk2bf(f0.z, f0.w);
        au[2] = pk2bf(f1.x, f1.y);
        au[3] = pk2bf(f1.z, f1.w);
      }
    } else {
#pragma unroll
      for (int mi = 0; mi < 2; ++mi) {
        const int m = mh * 2 + mi;
        const float* xr = x + (size_t)(n * C_ + m * 16 + cl) * P_;
#pragma unroll
        for (int j = 0; j < 8; ++j) {
          int idx = t * 27 + lq * 8 + j;
          idx = (idx < P_) ? idx : (P_ - 1);
          ax[mi][j] = (short)f2bf(xr[idx]);
        }
      }
    }
#pragma unroll
    for (int s = 0; s < 2; ++s) {
#pragma unroll
      for (int vt = 0; vt < 2; ++vt) {
        const int v = vt * 16 + cl;
#pragma unroll
        for (int mi = 0; mi < 2; ++mi) {
          const int m = mh * 2 + mi;
          fx4 z; z[0] = 0.f; z[1] = 0.f; z[2] = 0.f; z[3] = 0.f;
          fx4 dacc = __builtin_amdgcn_mfma_f32_16x16x32_bf16(ax[mi], batt[s][vt], z, 0, 0, 0);
          if (v < V_) {
            uint2 d;
            d.x = pk2bf(dacc[0], dacc[1]);
            d.y = pk2bf(dacc[2], dacc[3]);
            int row = th * 27 + v;
            int byteoff = row * 256 + (((s * 64 + m * 16 + lq * 4) * 2) ^ ((row & 7) << 4));
            *reinterpret_cast<uint2*>(zstg + byteoff) = d;
          }
        }
      }
    }
  }
  __syncthreads();

  // ---- phase3: y3 = Wout(64x128) . Z ----
  const int rl = w * 16 + cl;
  const int pidx = pbase + ((rl < 108) ? rl : 107);
  const int swz = (cl & 7) << 4;
  bhalf8 bfr[4];
#pragma unroll
  for (int ks = 0; ks < 4; ++ks)
    bfr[ks] = *reinterpret_cast<const bhalf8*>(zstg + rl * 256 + ((ks * 64 + lq * 16) ^ ((rl & 7) << 4)));
  fx4 acc[4];
#pragma unroll
  for (int m = 0; m < 4; ++m) { acc[m][0]=0.f; acc[m][1]=0.f; acc[m][2]=0.f; acc[m][3]=0.f; }
#pragma unroll
  for (int m = 0; m < 4; ++m) {
    const int row = m * 16 + cl;
#pragma unroll
    for (int ks = 0; ks < 4; ++ks) {
      bhalf8 a = *reinterpret_cast<const bhalf8*>(wout + row * 256 + ((ks * 64 + lq * 16) ^ ((row & 7) << 4)));
      acc[m] = __builtin_amdgcn_mfma_f32_16x16x32_bf16(a, bfr[ks], acc[m], 0, 0, 0);
    }
  }

  float xres[4][4];
#pragma unroll
  for (int m = 0; m < 4; ++m) {
    float h[4];
#pragma unroll
    for (int r = 0; r < 4; ++r) {
      int o = m * 16 + lq * 4 + r;
      float xv = x[((size_t)(n * C_ + o)) * (size_t)P_ + pidx];
      xres[m][r] = xv;
      float hv = acc[m][r] * clds[o] + clds[64 + o] + xv;
      h[r] = (hv >= 0.f) ? hv : 0.1f * hv;
    }
    uint2 d;
    d.x = pk2bf(h[0], h[1]);
    d.y = pk2bf(h[2], h[3]);
    int byteoff = rl * 128 + ((m * 32 + lq * 8) ^ swz);
    *reinterpret_cast<uint2*>(reinterpret_cast<char*>(h1t) + byteoff) = d;
  }

  // ---- phase4: f = Wff(64x64) . H1 (wave-local rows) ----
  fx4 acc2[4];
#pragma unroll
  for (int m = 0; m < 4; ++m) { acc2[m][0]=0.f; acc2[m][1]=0.f; acc2[m][2]=0.f; acc2[m][3]=0.f; }
#pragma unroll
  for (int ks = 0; ks < 2; ++ks) {
    int byteoff = rl * 128 + ((ks * 64 + lq * 16) ^ swz);
    bhalf8 b = *reinterpret_cast<const bhalf8*>(reinterpret_cast<char*>(h1t) + byteoff);
#pragma unroll
    for (int m = 0; m < 4; ++m) {
      const int row = m * 16 + cl;
      bhalf8 a = *reinterpret_cast<const bhalf8*>(wffl + row * 128 + ((ks * 64 + lq * 16) ^ ((row & 7) << 4)));
      acc2[m] = __builtin_amdgcn_mfma_f32_16x16x32_bf16(a, b, acc2[m], 0, 0, 0);
    }
  }

#pragma unroll
  for (int m = 0; m < 4; ++m) {
    float h[4];
#pragma unroll
    for (int r = 0; r < 4; ++r) {
      int o = m * 16 + lq * 4 + r;
      float hv = acc2[m][r] * clds[128 + o] + clds[192 + o] + xres[m][r];
      h[r] = (hv >= 0.f) ? hv : 0.1f * hv;
    }
    uint2 d;
    d.x = pk2bf(h[0], h[1]);
    d.y = pk2bf(h[2], h[3]);
    int byteoff = rl * 128 + ((m * 32 + lq * 8) ^ swz);
    *reinterpret_cast<uint2*>(reinterpret_cast<char*>(h1t) + byteoff) = d;
  }
  __syncthreads();

  {
    int row = tid >> 2, ch = tid & 3;
    if (row < 108) {
      int sw = (row & 7) << 4;
      uint4 d0 = *reinterpret_cast<uint4*>(reinterpret_cast<char*>(h1t) + row * 128 + (((2 * ch) * 16) ^ sw));
      uint4 d1 = *reinterpret_cast<uint4*>(reinterpret_cast<char*>(h1t) + row * 128 + (((2 * ch + 1) * 16) ^ sw));
      char* dst = reinterpret_cast<char*>(h2Tg) + ((size_t)n * HROWS + HGUARD + pbase + row) * 128 + ch * 32;
      *reinterpret_cast<uint4*>(dst) = d0;
      *reinterpret_cast<uint4*>(dst + 16) = d1;
    }
  }
}

// k4c: LDS-staged temporal conv K=192 MFMA GEMM + bn3/res/lrelu -> out
// 512 threads, 128-p tile (+/-32 halo).
__global__ __launch_bounds__(512) void k4c(
    const unsigned short* __restrict__ h2Tg,
    const unsigned short* __restrict__ Wtb,
    const float* __restrict__ cst,
    float* __restrict__ out)
{
  const int n = blockIdx.x;
  const int p0 = blockIdx.y * 128;
  const int tid = threadIdx.x;
  const int w = tid >> 6;
  const int l = tid & 63;
  const int cl = l & 15;
  const int lq = l >> 4;
  const int p = p0 + w * 16 + cl;

  __shared__ __align__(16) char hst[24576];
  __shared__ __align__(16) char wst[24576];
  __shared__ float clds[128];
  if (tid < 128) clds[tid] = cst[256 + tid];

  const unsigned short* hbase = h2Tg + ((size_t)n * HROWS + HGUARD + p0 - 32) * 64;
  for (int i = tid; i < 1536; i += 512) {
    int r = i >> 3, ch = i & 7;
    uint4 d = *reinterpret_cast<const uint4*>(hbase + (size_t)r * 64 + ch * 8);
    *reinterpret_cast<uint4*>(hst + r * 128 + ((ch * 16) ^ ((r & 7) << 4))) = d;
  }
  for (int i = tid; i < 1536; i += 512) {
    int r = i / 24, ch = i - r * 24;
    uint4 d = *reinterpret_cast<const uint4*>(Wtb + r * 192 + ch * 8);
    *reinterpret_cast<uint4*>(wst + r * 384 + ((ch * 16) ^ ((r & 7) << 4))) = d;
  }
  __syncthreads();

  const int rl = 32 + w * 16 + cl;
  bhalf8 bfr[6];
#pragma unroll
  for (int ks = 0; ks < 6; ++ks) {
    int k0 = ks * 32 + lq * 8;
    int dt = k0 >> 6;
    int i0 = k0 & 63;
    int rr = rl + (dt - 1) * 27;
    bfr[ks] = *reinterpret_cast<const bhalf8*>(hst + rr * 128 + ((2 * i0) ^ ((rr & 7) << 4)));
  }
  fx4 acc[4];
#pragma unroll
  for (int m = 0; m < 4; ++m) { acc[m][0]=0.f; acc[m][1]=0.f; acc[m][2]=0.f; acc[m][3]=0.f; }
#pragma unroll
  for (int m = 0; m < 4; ++m) {
    const int row = m * 16 + cl;
#pragma unroll
    for (int ks = 0; ks < 6; ++ks) {
      bhalf8 a = *reinterpret_cast<const bhalf8*>(wst + row * 384 + ((ks * 64 + lq * 16) ^ ((row & 7) << 4)));
      acc[m] = __builtin_amdgcn_mfma_f32_16x16x32_bf16(a, bfr[ks], acc[m], 0, 0, 0);
    }
  }
  if (p < P_) {
#pragma unroll
    for (int m = 0; m < 4; ++m) {
      uint2 hr = *reinterpret_cast<uint2*>(hst + rl * 128 + (((m * 16 + lq * 4) * 2) ^ ((rl & 7) << 4)));
      float hc[4];
      hc[0] = bf2f((unsigned short)(hr.x & 0xffff));
      hc[1] = bf2f((unsigned short)(hr.x >> 16));
      hc[2] = bf2f((unsigned short)(hr.y & 0xffff));
      hc[3] = bf2f((unsigned short)(hr.y >> 16));
#pragma unroll
      for (int r = 0; r < 4; ++r) {
        int o = m * 16 + lq * 4 + r;
        float val = acc[m][r] * clds[o] + clds[64 + o] + hc[r];
        val = (val >= 0.f) ? val : 0.1f * val;
        out[((size_t)(n * CO_ + o)) * (size_t)P_ + p] = val;
      }
    }
  }
}

// ================= fallback path =================
__global__ __launch_bounds__(256) void k1_qk_partial(
    const float* __restrict__ x, const float* __restrict__ pe,
    const float* __restrict__ w_in, const float* __restrict__ b_in,
    float* __restrict__ partial)
{
  const int n = blockIdx.x;
  const int chunk = blockIdx.y;
  const int tid = threadIdx.x;
  __shared__ float ylds[C_][28];
  __shared__ float qlds[C_][28];
  __shared__ float wlds[C_][65];
  for (int i = tid; i < C_ * C_; i += 256) wlds[i >> 6][i & 63] = w_in[i];
  float acc[6];
#pragma unroll
  for (int j = 0; j < 6; ++j) acc[j] = 0.f;
  const int t0 = chunk * TCHUNK;
  for (int tt = 0; tt < TCHUNK; ++tt) {
    const int t = t0 + tt;
    __syncthreads();
    for (int i = tid; i < C_ * V_; i += 256) {
      int c = i / V_, v = i - c * V_;
      ylds[c][v] = x[((size_t)(n * C_ + c) * T_ + t) * V_ + v] + pe[(c * T_ + t) * V_ + v];
    }
    __syncthreads();
    for (int i = tid; i < C_ * V_; i += 256) {
      int o = i / V_, v = i - o * V_;
      float s = b_in[o];
#pragma unroll
      for (int c = 0; c < C_; ++c) s += wlds[o][c] * ylds[c][v];
      qlds[o][v] = s;
    }
    __syncthreads();
#pragma unroll
    for (int j = 0; j < 6; ++j) {
      int i = tid + j * 256;
      if (i < ATT_N) {
        int s = i / 729, r = i - s * 729, u = r / 27, v = r - u * 27;
        float a = 0.f;
#pragma unroll
        for (int c = 0; c < CI_; ++c)
          a += qlds[s * CI_ + c][u] * qlds[S_ * CI_ + s * CI_ + c][v];
        acc[j] += a;
      }
    }
  }
  float* dst = partial + (size_t)(n * NCHUNK + chunk) * ATT_N;
#pragma unroll
  for (int j = 0; j < 6; ++j) {
    int i = tid + j * 256;
    if (i < ATT_N) dst[i] = acc[j];
  }
}

__global__ __launch_bounds__(256) void k2_att_fin(
    const float* __restrict__ partial, const float* __restrict__ alphas,
    const float* __restrict__ att0, float* __restrict__ att)
{
  int i = blockIdx.x * 256 + threadIdx.x;
  if (i >= N_ * ATT_N) return;
  int n = i / ATT_N, r = i - n * ATT_N;
  int s = r / 729;
  float a = 0.f;
  const float* p = partial + (size_t)n * NCHUNK * ATT_N + r;
  for (int ch = 0; ch < NCHUNK; ++ch) a += p[(size_t)ch * ATT_N];
  a = tanhf(a * (1.0f / (CI_ * (float)T_))) * alphas[s] + att0[r];
  att[i] = a;
}

__global__ __launch_bounds__(256) void k3a(
    const float* __restrict__ x, const float* __restrict__ att,
    const float* __restrict__ w_out, const float* __restrict__ b_out,
    const float* __restrict__ bn1_g, const float* __restrict__ bn1_b,
    const float* __restrict__ bn1_m, const float* __restrict__ bn1_v,
    const float* __restrict__ w_ff, const float* __restrict__ b_ff,
    const float* __restrict__ bn2_g, const float* __restrict__ bn2_b,
    const float* __restrict__ bn2_m, const float* __restrict__ bn2_v,
    float* __restrict__ h2g)
{
  const int n = blockIdx.x;
  const int t0 = blockIdx.y * 2;
  const int tid = threadIdx.x;
  const int v = tid & 31;
  const int tloc = (tid >> 5) & 1;
  const int col = tid & 63;
  const int rg = __builtin_amdgcn_readfirstlane(tid >> 6);
  const int t = t0 + tloc;

  __shared__ float xlds[C_][64];
  __shared__ float zlds[S_ * C_][64];

  for (int i = tid; i < C_ * 64; i += 256) {
    int c = i >> 6, cl = i & 63, tl = cl >> 5, vv = cl & 31;
    xlds[c][cl] = (vv < V_) ? x[((size_t)(n * C_ + c) * T_ + t0 + tl) * V_ + vv] : 0.f;
  }
  float attreg[S_][V_];
  {
    const float* ab = att + (size_t)n * ATT_N + v;
#pragma unroll
    for (int s = 0; s < S_; ++s)
#pragma unroll
      for (int u = 0; u < V_; ++u)
        attreg[s][u] = (v < V_) ? ab[s * 729 + u * 27] : 0.f;
  }
  __syncthreads();
#pragma unroll 1
  for (int cc = 0; cc < 16; ++cc) {
    const int c = rg * 16 + cc;
    float xr[V_];
#pragma unroll
    for (int u = 0; u < V_; ++u) xr[u] = xlds[c][tloc * 32 + u];
    float a0 = 0.f, a1 = 0.f;
#pragma unroll
    for (int u = 0; u < V_; ++u) {
      a0 += xr[u] * attreg[0][u];
      a1 += xr[u] * attreg[1][u];
    }
    zlds[c][col] = a0;
    zlds[C_ + c][col] = a1;
  }
  __syncthreads();
  float acc[16];
#pragma unroll
  for (int oo = 0; oo < 16; ++oo) acc[oo] = 0.f;
#pragma unroll 1
  for (int kc = 0; kc < 4; ++kc) {
    float zk[32];
#pragma unroll
    for (int j = 0; j < 32; ++j) zk[j] = zlds[kc * 32 + j][col];
#pragma unroll
    for (int oo = 0; oo < 16; ++oo) {
      const float* wr = w_out + (rg * 16 + oo) * (S_ * C_) + kc * 32;
      float s = acc[oo];
#pragma unroll
      for (int j = 0; j < 32; ++j) s += wr[j] * zk[j];
      acc[oo] = s;
    }
  }
  float h1v[16];
#pragma unroll
  for (int oo = 0; oo < 16; ++oo) {
    const int o = rg * 16 + oo;
    float y3 = acc[oo] + b_out[o];
    float h = (y3 - bn1_m[o]) * (bn1_g[o] * rsqrtf(bn1_v[o] + 1e-5f)) + bn1_b[o]
              + xlds[o][col];
    h1v[oo] = (h >= 0.f) ? h : 0.1f * h;
  }
  __syncthreads();
#pragma unroll
  for (int oo = 0; oo < 16; ++oo) zlds[rg * 16 + oo][col] = h1v[oo];
  __syncthreads();
#pragma unroll
  for (int oo = 0; oo < 16; ++oo) acc[oo] = 0.f;
#pragma unroll 1
  for (int kc = 0; kc < 2; ++kc) {
    float zk[32];
#pragma unroll
    for (int j = 0; j < 32; ++j) zk[j] = zlds[kc * 32 + j][col];
#pragma unroll
    for (int oo = 0; oo < 16; ++oo) {
      const float* wr = w_ff + (rg * 16 + oo) * C_ + kc * 32;
      float s = acc[oo];
#pragma unroll
      for (int j = 0; j < 32; ++j) s += wr[j] * zk[j];
      acc[oo] = s;
    }
  }
  if (v < V_) {
#pragma unroll
    for (int oo = 0; oo < 16; ++oo) {
      const int o = rg * 16 + oo;
      float f = acc[oo] + b_ff[o];
      float h = (f - bn2_m[o]) * (bn2_g[o] * rsqrtf(bn2_v[o] + 1e-5f)) + bn2_b[o]
                + xlds[o][col];
      h2g[((size_t)(n * CO_ + o) * T_ + t) * V_ + v] = (h >= 0.f) ? h : 0.1f * h;
    }
  }
}

__global__ __launch_bounds__(256) void k3b(
    const float* __restrict__ h2g, const float* __restrict__ w_t,
    const float* __restrict__ b_t,
    const float* __restrict__ bn3_g, const float* __restrict__ bn3_b,
    const float* __restrict__ bn3_m, const float* __restrict__ bn3_v,
    float* __restrict__ out)
{
  const int n = blockIdx.x;
  const int t0 = blockIdx.y * 2;
  const int tid = threadIdx.x;
  const int v = tid & 31;
  const int tloc = (tid >> 5) & 1;
  const int rg = __builtin_amdgcn_readfirstlane(tid >> 6);
  const int t = t0 + tloc;

  __shared__ float hl[C_][4][32];

  for (int idx = tid; idx < C_ * 4 * 32; idx += 256) {
    int i = idx >> 7, r = idx & 127, sl = r >> 5, vv = r & 31;
    int tg = t0 - 1 + sl;
    hl[i][sl][vv] = (vv < V_ && tg >= 0 && tg < T_)
                    ? h2g[((size_t)(n * CO_ + i) * T_ + tg) * V_ + vv] : 0.f;
  }
  __syncthreads();

  float acc[16];
#pragma unroll
  for (int oo = 0; oo < 16; ++oo) acc[oo] = 0.f;
#pragma unroll 1
  for (int ic = 0; ic < 4; ++ic) {
    float h[16][3];
#pragma unroll
    for (int ii = 0; ii < 16; ++ii) {
      h[ii][0] = hl[ic * 16 + ii][tloc][v];
      h[ii][1] = hl[ic * 16 + ii][tloc + 1][v];
      h[ii][2] = hl[ic * 16 + ii][tloc + 2][v];
    }
#pragma unroll
    for (int oo = 0; oo < 16; ++oo) {
      const float* wr = w_t + ((size_t)(rg * 16 + oo) * C_ + ic * 16) * 3;
      float s = acc[oo];
#pragma unroll
      for (int ii = 0; ii < 16; ++ii) {
        s += wr[ii * 3 + 0] * h[ii][0]
           + wr[ii * 3 + 1] * h[ii][1]
           + wr[ii * 3 + 2] * h[ii][2];
      }
      acc[oo] = s;
    }
  }
  if (v < V_) {
#pragma unroll
    for (int oo = 0; oo < 16; ++oo) {
      const int o = rg * 16 + oo;
      float zv = acc[oo] + b_t[o];
      float r = (zv - bn3_m[o]) * (bn3_g[o] * rsqrtf(bn3_v[o] + 1e-5f)) + bn3_b[o]
                + hl[o][tloc + 1][v];
      out[((size_t)(n * CO_ + o) * T_ + t) * V_ + v] = (r >= 0.f) ? r : 0.1f * r;
    }
  }
}

extern "C" void kernel_launch(void* const* d_in, const int* in_sizes, int n_in,
                              void* d_out, int out_size, void* d_ws, size_t ws_size,
                              hipStream_t stream)
{
  (void)in_sizes; (void)n_in; (void)out_size;
  const float* x      = (const float*)d_in[0];
  const float* pe     = (const float*)d_in[1];
  const float* w_in   = (const float*)d_in[2];
  const float* b_in   = (const float*)d_in[3];
  const float* alphas = (const float*)d_in[4];
  const float* att0   = (const float*)d_in[5];
  const float* w_out  = (const float*)d_in[6];
  const float* b_out  = (const float*)d_in[7];
  const float* bn1_g  = (const float*)d_in[8];
  const float* bn1_b  = (const float*)d_in[9];
  const float* bn1_m  = (const float*)d_in[10];
  const float* bn1_v  = (const float*)d_in[11];
  const float* w_ff   = (const float*)d_in[12];
  const float* b_ff   = (const float*)d_in[13];
  const float* bn2_g  = (const float*)d_in[14];
  const float* bn2_b  = (const float*)d_in[15];
  const float* bn2_m  = (const float*)d_in[16];
  const float* bn2_v  = (const float*)d_in[17];
  const float* w_t    = (const float*)d_in[18];
  const float* b_t    = (const float*)d_in[19];
  const float* bn3_g  = (const float*)d_in[20];
  const float* bn3_b  = (const float*)d_in[21];
  const float* bn3_m  = (const float*)d_in[22];
  const float* bn3_v  = (const float*)d_in[23];
  float* out = (float*)d_out;

  char* ws = (char*)d_ws;
  unsigned short* Wb   = (unsigned short*)(ws);              // 57,344 B
  float*          cst  = (float*)(ws + 57344);               // 1,792 B
  unsigned short* attT = (unsigned short*)(ws + 59136);      // 131,072 B
  float*          pws  = (float*)(ws + 190208);              // 1,048,576 B
  unsigned short* qk2  = (unsigned short*)(ws + 1238784);    // 44,302,336 B
  unsigned short* h2T  = (unsigned short*)(ws + 45541120);   // 44,826,624 B
  const size_t need_mfma = 90367744;
  const size_t need_old  = ((size_t)N_ * NCHUNK * ATT_N + (size_t)N_ * ATT_N
                            + (size_t)N_ * CO_ * T_ * V_) * sizeof(float);

  if (ws_size >= need_mfma) {
    kprep<<<64, 256, 0, stream>>>(w_out, w_ff, w_t, w_in, b_out, b_ff, b_t, b_in,
        bn1_g, bn1_b, bn1_m, bn1_v, bn2_g, bn2_b, bn2_m, bn2_v,
        bn3_g, bn3_b, bn3_m, bn3_v, Wb, cst, h2T);
    k1a2<<<dim3(N_, QTILES), 256, 0, stream>>>(x, pe, Wb, cst, qk2);
    k1b<<<dim3(64, 4), 256, 0, stream>>>(qk2, pws);
    k1c<<<256, 256, 0, stream>>>(pws, alphas, att0, attT);
    kz4b<<<dim3(N_, T_ / 4), 512, 0, stream>>>(x, attT, Wb, cst, h2T);
    k4c<<<dim3(N_, QTILES), 512, 0, stream>>>(h2T, Wb + 12288, cst, out);
  } else if (ws_size >= need_old) {
    float* partial = (float*)ws;
    float* att     = partial + (size_t)N_ * NCHUNK * ATT_N;
    float* h2g     = att + (size_t)N_ * ATT_N;
    k1_qk_partial<<<dim3(N_, NCHUNK), 256, 0, stream>>>(x, pe, w_in, b_in, partial);
    k2_att_fin<<<(N_ * ATT_N + 255) / 256, 256, 0, stream>>>(partial, alphas, att0, att);
    k3a<<<dim3(N_, T_ / 2), 256, 0, stream>>>(x, att,
        w_out, b_out, bn1_g, bn1_b, bn1_m, bn1_v,
        w_ff, b_ff, bn2_g, bn2_b, bn2_m, bn2_v, h2g);
    k3b<<<dim3(N_, T_ / 2), 256, 0, stream>>>(h2g, w_t, b_t,
        bn3_g, bn3_b, bn3_m, bn3_v, out);
  }
}